// Round 8
// baseline (811.170 us; speedup 1.0000x reference)
//
#include <hip/hip_runtime.h>

typedef unsigned int u32;

// GCN, 2-layer (16->16 relu, 16->8), DGL GraphConv norm='both', self-loops.
// N = 100000 nodes, E = 3.2M edges, f32, edge_index int32.
// Round 8: src-bucketed scatter kept (9.4MB L2-hot gathers, round 7), but the
// per-item 10-step LDS binary search (512M ds_reads!) replaced by a one-time
// bisect + register-cached linear bucket advance; item granularity = float2
// (halves part-loads and index VALU; atomic count unchanged).

constexpr int F1 = 16;
constexpr int F2 = 8;
constexpr int HIST_N   = 100000;        // specialized node count
constexpr int HIST_U32 = HIST_N / 4;    // 25000 packed-u8 words
constexpr int NB_HIST  = 256;           // one hist block per CU
constexpr int RB       = 128;           // nodes per src bucket
constexpr int NBUCK    = (HIST_N + RB - 1) / RB;  // 782
constexpr int P2B      = 512;           // partition/count blocks
constexpr int SCB      = 2048;          // scatter blocks (divisible by 8)

// ---- dst-degree: LDS packed-u8 histogram + byte-sum merge -> norm_dst ----

__global__ void __launch_bounds__(256) hist_kernel(const int* __restrict__ idx,
                                                   u32* __restrict__ partial,
                                                   int nE, int per_block) {
    __shared__ u32 h[HIST_U32];
    for (int i = threadIdx.x; i < HIST_U32; i += 256) h[i] = 0u;
    __syncthreads();
    const int beg = blockIdx.x * per_block;
    const int end = min(nE, beg + per_block);
    for (int base = beg; base < end; base += 256 * 4) {
        int i = base + threadIdx.x * 4;
        if (i + 3 < end) {
            int4 v = *reinterpret_cast<const int4*>(idx + i);
            atomicAdd(&h[v.x >> 2], 1u << ((v.x & 3) << 3));
            atomicAdd(&h[v.y >> 2], 1u << ((v.y & 3) << 3));
            atomicAdd(&h[v.z >> 2], 1u << ((v.z & 3) << 3));
            atomicAdd(&h[v.w >> 2], 1u << ((v.w & 3) << 3));
        } else {
#pragma unroll
            for (int k = 0; k < 4; ++k)
                if (i + k < end) {
                    int v = idx[i + k];
                    atomicAdd(&h[v >> 2], 1u << ((v & 3) << 3));
                }
        }
    }
    __syncthreads();
    u32* out = partial + (size_t)blockIdx.x * HIST_U32;
    for (int i = threadIdx.x; i < HIST_U32; i += 256) out[i] = h[i];
}

__global__ void __launch_bounds__(256) merge_norm_kernel(const u32* __restrict__ partial,
                                                         float* __restrict__ norm) {
    int t = blockIdx.x * 256 + threadIdx.x;
    if (t >= HIST_U32) return;
    u32 s0 = 0, s1 = 0, s2 = 0, s3 = 0;
    const u32* p = partial + t;
    for (int b = 0; b < NB_HIST; ++b) {
        u32 v = p[(size_t)b * HIST_U32];
        s0 += v & 0xffu; s1 += (v >> 8) & 0xffu;
        s2 += (v >> 16) & 0xffu; s3 += v >> 24;
    }
    float4 o = make_float4(rsqrtf(1.f + (float)s0), rsqrtf(1.f + (float)s1),
                           rsqrtf(1.f + (float)s2), rsqrtf(1.f + (float)s3));
    *reinterpret_cast<float4*>(norm + (size_t)t * 4) = o;
}

// ---- src-bucket counting sort ----

__global__ void __launch_bounds__(256) bucket_count_kernel(const int* __restrict__ src,
                                                           u32* __restrict__ bcnt, int nE) {
    __shared__ u32 c[NBUCK];
    for (int j = threadIdx.x; j < NBUCK; j += 256) c[j] = 0;
    __syncthreads();
    for (int i = blockIdx.x * 256 + threadIdx.x; i < nE; i += 256 * P2B)
        atomicAdd(&c[src[i] >> 7], 1u);
    __syncthreads();
    for (int j = threadIdx.x; j < NBUCK; j += 256)
        if (c[j]) atomicAdd(&bcnt[j], c[j]);
}

__global__ void __launch_bounds__(1024) bucket_scan_kernel(const u32* __restrict__ bcnt,
                                                           u32* __restrict__ bbase,
                                                           u32* __restrict__ bcur) {
    __shared__ u32 s[1024];
    int t = threadIdx.x;
    u32 v = (t < NBUCK) ? bcnt[t] : 0;
    s[t] = v;
    __syncthreads();
    for (int off = 1; off < 1024; off <<= 1) {
        u32 a = (t >= off) ? s[t - off] : 0;
        __syncthreads();
        s[t] += a;
        __syncthreads();
    }
    if (t < NBUCK) {
        u32 ex = s[t] - v;
        bbase[t] = ex;
        bcur[t] = ex;
        if (t == NBUCK - 1) bbase[NBUCK] = s[t];
    }
}

// pack: (src_local<<17) | dst   (dst < 2^17, src_local < 128)
__global__ void __launch_bounds__(256) partition_kernel(const int* __restrict__ src,
                                                        const int* __restrict__ dst,
                                                        u32* __restrict__ part,
                                                        u32* __restrict__ bcur,
                                                        int nE, int per_block) {
    __shared__ u32 cnt[NBUCK];
    __shared__ u32 gb[NBUCK];
    for (int j = threadIdx.x; j < NBUCK; j += 256) cnt[j] = 0;
    __syncthreads();
    const int beg = blockIdx.x * per_block;
    const int end = min(nE, beg + per_block);
    for (int i = beg + threadIdx.x; i < end; i += 256)
        atomicAdd(&cnt[src[i] >> 7], 1u);
    __syncthreads();
    for (int j = threadIdx.x; j < NBUCK; j += 256) {
        u32 c = cnt[j];
        gb[j] = c ? atomicAdd(&bcur[j], c) : 0u;
        cnt[j] = 0;
    }
    __syncthreads();
    for (int i = beg + threadIdx.x; i < end; i += 256) {
        int s = src[i];
        int b = s >> 7;
        u32 r = atomicAdd(&cnt[b], 1u);
        part[gb[b] + r] = ((u32)(s & 127) << 17) | (u32)dst[i];
    }
}

// norm_src from partitioned edges: per-bucket src_local counts
__global__ void __launch_bounds__(256) norm_src_kernel(const u32* __restrict__ part,
                                                       const u32* __restrict__ bbase,
                                                       float* __restrict__ norm_src, int n) {
    __shared__ u32 c[RB];
    if (threadIdx.x < RB) c[threadIdx.x] = 0;
    __syncthreads();
    u32 beg = bbase[blockIdx.x], end = bbase[blockIdx.x + 1];
    for (u32 j = beg + threadIdx.x; j < end; j += 256)
        atomicAdd(&c[part[j] >> 17], 1u);
    __syncthreads();
    if (threadIdx.x < RB) {
        int node = blockIdx.x * RB + threadIdx.x;
        if (node < n) norm_src[node] = rsqrtf(1.f + (float)c[threadIdx.x]);
    }
}

// ---- scatter: gather h[src] (L1/L2-hot via src-bucketed order), global
// atomicAdd to agg[dst]. One item = (edge, float2 feature pair). Bucket id via
// one-time bisect + register-cached linear advance (per-thread e is monotone).
template <int F>
__global__ void __launch_bounds__(256) scatter_bucketed_kernel(
        const u32* __restrict__ part, const u32* __restrict__ bbase_g,
        const float* __restrict__ h, float* __restrict__ agg, int nE) {
    __shared__ u32 bb[NBUCK + 1];
    for (int i = threadIdx.x; i < NBUCK + 1; i += 256) bb[i] = bbase_g[i];
    __syncthreads();
    // bijective XCD swizzle: each XCD gets a contiguous chunk of blocks ->
    // contiguous src-bucket range -> exclusive L2 window.
    const int nb = (int)gridDim.x;
    const int q = nb / 8, r = nb % 8;
    const int xc = (int)blockIdx.x % 8, ix = (int)blockIdx.x / 8;
    const int sb = (xc < r ? xc * (q + 1) : r * (q + 1) + (xc - r) * q) + ix;

    constexpr int F2V = F / 2;                    // float2 items per edge
    constexpr int fsh = (F == 16) ? 3 : 2;        // log2(F2V)
    const long long total = (long long)nE * F2V;
    const long long per = (total + nb - 1) / nb;
    const long long beg = (long long)sb * per;
    const long long end = (beg + per < total) ? beg + per : total;

    long long t0 = beg + threadIdx.x;
    if (t0 >= end) return;
    // one-time bisect: bb[lo] <= e0 < bb[lo+1]
    int e0 = (int)(t0 >> fsh);
    int lo = 0, hi = NBUCK;
#pragma unroll
    for (int s = 0; s < 10; ++s) {
        int mid = (lo + hi) >> 1;
        if (bb[mid] <= (u32)e0) lo = mid; else hi = mid;
    }
    u32 nextb = bb[lo + 1];
    for (long long t = t0; t < end; t += 256) {
        int e = (int)(t >> fsh);
        int f2 = (int)(t & (F2V - 1));
        while ((u32)e >= nextb) { ++lo; nextb = bb[lo + 1]; }
        u32 w = __builtin_nontemporal_load(part + e);
        int s = lo * RB + (int)(w >> 17);
        int d = (int)(w & 0x1FFFFu);
        float2 v = *reinterpret_cast<const float2*>(h + (size_t)s * F + 2 * f2);
        float* ap = agg + (size_t)d * F + 2 * f2;
        atomicAdd(ap, v.x);
        atomicAdd(ap + 1, v.y);
    }
}

// ---- dense transforms ----

__global__ void xw16_kernel(const float* __restrict__ x, const float* __restrict__ W,
                            const float* __restrict__ norm_src,
                            float* __restrict__ h, int n) {
    __shared__ float Ws[256];
    int t = threadIdx.x;
    if (t < 256) Ws[t] = W[t];
    __syncthreads();
    int i = blockIdx.x * blockDim.x + t;
    if (i >= n) return;
    float xi[16];
    const float4* xp = reinterpret_cast<const float4*>(x + (size_t)i * 16);
    float4 v;
    v = xp[0]; xi[0]=v.x; xi[1]=v.y; xi[2]=v.z; xi[3]=v.w;
    v = xp[1]; xi[4]=v.x; xi[5]=v.y; xi[6]=v.z; xi[7]=v.w;
    v = xp[2]; xi[8]=v.x; xi[9]=v.y; xi[10]=v.z; xi[11]=v.w;
    v = xp[3]; xi[12]=v.x; xi[13]=v.y; xi[14]=v.z; xi[15]=v.w;
    float ns = norm_src[i];
    float o[16];
#pragma unroll
    for (int j = 0; j < 16; ++j) {
        float acc = 0.f;
#pragma unroll
        for (int k = 0; k < 16; ++k) acc = fmaf(xi[k], Ws[k * 16 + j], acc);
        o[j] = acc * ns;
    }
    float4* hp = reinterpret_cast<float4*>(h + (size_t)i * 16);
    hp[0] = make_float4(o[0], o[1], o[2], o[3]);
    hp[1] = make_float4(o[4], o[5], o[6], o[7]);
    hp[2] = make_float4(o[8], o[9], o[10], o[11]);
    hp[3] = make_float4(o[12], o[13], o[14], o[15]);
}

__global__ void xw8_kernel(const float* __restrict__ x, const float* __restrict__ W,
                           const float* __restrict__ norm_src,
                           float* __restrict__ h, int n) {
    __shared__ float Ws[128];
    int t = threadIdx.x;
    if (t < 128) Ws[t] = W[t];
    __syncthreads();
    int i = blockIdx.x * blockDim.x + t;
    if (i >= n) return;
    float xi[16];
    const float4* xp = reinterpret_cast<const float4*>(x + (size_t)i * 16);
    float4 v;
    v = xp[0]; xi[0]=v.x; xi[1]=v.y; xi[2]=v.z; xi[3]=v.w;
    v = xp[1]; xi[4]=v.x; xi[5]=v.y; xi[6]=v.z; xi[7]=v.w;
    v = xp[2]; xi[8]=v.x; xi[9]=v.y; xi[10]=v.z; xi[11]=v.w;
    v = xp[3]; xi[12]=v.x; xi[13]=v.y; xi[14]=v.z; xi[15]=v.w;
    float ns = norm_src[i];
    float o[8];
#pragma unroll
    for (int j = 0; j < 8; ++j) {
        float acc = 0.f;
#pragma unroll
        for (int k = 0; k < 16; ++k) acc = fmaf(xi[k], Ws[k * 8 + j], acc);
        o[j] = acc * ns;
    }
    float4* hp = reinterpret_cast<float4*>(h + (size_t)i * 8);
    hp[0] = make_float4(o[0], o[1], o[2], o[3]);
    hp[1] = make_float4(o[4], o[5], o[6], o[7]);
}

// out = ((agg + h_self) * norm_dst + b), optional relu (elementwise, in-place ok)
template <int F, bool RELU>
__global__ void combine_kernel(const float* __restrict__ agg, const float* __restrict__ h,
                               const float* __restrict__ norm_dst,
                               const float* __restrict__ b,
                               float* __restrict__ out, int n) {
    int t = blockIdx.x * 256 + threadIdx.x;
    if (t >= n * F) return;
    int i = t / F;
    int f = t % F;
    float v = (agg[t] + h[t]) * norm_dst[i] + b[f];
    if (RELU) v = fmaxf(v, 0.f);
    out[t] = v;
}

// ---- fallback (n != 100000 or small ws): scattered-atomic path ----

__global__ void init_deg_kernel(float* __restrict__ a, float* __restrict__ b, int n) {
    int i = blockIdx.x * 256 + threadIdx.x;
    if (i < n) { a[i] = 1.0f; b[i] = 1.0f; }
}
__global__ void count_deg_kernel(const int* __restrict__ src, const int* __restrict__ dst,
                                 float* __restrict__ dego, float* __restrict__ degi, int nE) {
    int e = blockIdx.x * 256 + threadIdx.x;
    if (e < nE) { atomicAdd(dego + src[e], 1.0f); atomicAdd(degi + dst[e], 1.0f); }
}
__global__ void rsqrt_kernel(float* __restrict__ a, float* __restrict__ b, int n) {
    int i = blockIdx.x * 256 + threadIdx.x;
    if (i < n) { a[i] = rsqrtf(a[i]); b[i] = rsqrtf(b[i]); }
}
template <int F>
__global__ void scatter_kernel(const int* __restrict__ src, const int* __restrict__ dst,
                               const float* __restrict__ h, float* __restrict__ agg,
                               int nE) {
    long long t = (long long)blockIdx.x * blockDim.x + threadIdx.x;
    if (t >= (long long)nE * F) return;
    int e = (int)(t / F);
    int f = (int)(t % F);
    atomicAdd(agg + (size_t)dst[e] * F + f, h[(size_t)src[e] * F + f]);
}

extern "C" void kernel_launch(void* const* d_in, const int* in_sizes, int n_in,
                              void* d_out, int out_size, void* d_ws, size_t ws_size,
                              hipStream_t stream) {
    const float* x  = (const float*)d_in[0];
    const float* W1 = (const float*)d_in[1];
    const float* b1 = (const float*)d_in[2];
    const float* W2 = (const float*)d_in[3];
    const float* b2 = (const float*)d_in[4];
    const int*   ei = (const int*)d_in[5];

    const int n  = in_sizes[0] / F1;   // 100000
    const int nE = in_sizes[5] / 2;    // 3200000
    const int* src = ei;
    const int* dst = ei + nE;

    const size_t na = ((size_t)n + 63) & ~(size_t)63;
    const int B = 256;
    dim3 blk(B);
    int gN   = (int)((n + B - 1) / B);
    int gNF1 = (int)((n * (size_t)F1 + B - 1) / B);
    int gNF2 = (int)((n * (size_t)F2 + B - 1) / B);

    // fast-path workspace layout
    float* norm_src = (float*)d_ws;                  // [na]
    float* norm_dst = norm_src + na;                 // [na]
    u32*   bbase    = (u32*)(norm_dst + na);         // [1024]
    u32*   bcur     = bbase + 1024;                  // [1024]
    u32*   bcnt     = bcur + 1024;                   // [1024]
    u32*   part     = bcnt + 1024;                   // [nE]
    float* bufA     = (float*)(part + nE);           // [na*16] h1' then out1
    float* bufB     = bufA + na * F1;                // [na*16] agg1; then h2 | agg2
    u32*   partial  = part;                          // NB_HIST*HIST_U32 overlays part+buf
    size_t need = ((size_t)2 * na + 3 * 1024 + (size_t)nE + 32 * na) * 4;
    size_t need_hist = ((size_t)2 * na + 3 * 1024) * 4 + (size_t)NB_HIST * HIST_U32 * 4;
    if (need_hist > need) need = need_hist;

    if (n == HIST_N && ws_size >= need) {
        int per_hist = (nE + NB_HIST - 1) / NB_HIST;
        int per_p2   = (nE + P2B - 1) / P2B;
        int gM = (HIST_U32 + B - 1) / B;

        // norm_dst via u8-hist on dst (partial overlays part/buf region; done
        // before partition writes part)
        hist_kernel<<<NB_HIST, blk, 0, stream>>>(dst, partial, nE, per_hist);
        merge_norm_kernel<<<gM, blk, 0, stream>>>(partial, norm_dst);

        // counting sort of edges by src bucket (src>>7)
        hipMemsetAsync(bcnt, 0, NBUCK * sizeof(u32), stream);
        bucket_count_kernel<<<P2B, blk, 0, stream>>>(src, bcnt, nE);
        bucket_scan_kernel<<<1, 1024, 0, stream>>>(bcnt, bbase, bcur);
        partition_kernel<<<P2B, blk, 0, stream>>>(src, dst, part, bcur, nE, per_p2);
        norm_src_kernel<<<NBUCK, blk, 0, stream>>>(part, bbase, norm_src, n);

        // layer 1: h1' = xW1*norm_src; agg1 = A^T h1'; out1 = relu((agg1+h1')*nd+b1)
        xw16_kernel<<<gN, blk, 0, stream>>>(x, W1, norm_src, bufA, n);
        hipMemsetAsync(bufB, 0, (size_t)n * F1 * sizeof(float), stream);
        scatter_bucketed_kernel<F1><<<SCB, blk, 0, stream>>>(part, bbase, bufA, bufB, nE);
        combine_kernel<F1, true><<<gNF1, blk, 0, stream>>>(bufB, bufA, norm_dst, b1,
                                                           bufA, n);  // out1 -> bufA

        // layer 2: h2 = out1*W2*norm_src (bufB low half); agg2 = bufB high half
        float* h2   = bufB;
        float* agg2 = bufB + na * F2;
        xw8_kernel<<<gN, blk, 0, stream>>>(bufA, W2, norm_src, h2, n);
        hipMemsetAsync(agg2, 0, (size_t)n * F2 * sizeof(float), stream);
        scatter_bucketed_kernel<F2><<<SCB, blk, 0, stream>>>(part, bbase, h2, agg2, nE);
        combine_kernel<F2, false><<<gNF2, blk, 0, stream>>>(agg2, h2, norm_dst, b2,
                                                            (float*)d_out, n);
    } else {
        // fallback: scattered atomics (fits 13.7 MB ws)
        float* fnorm_src = (float*)d_ws;
        float* fnorm_dst = fnorm_src + na;
        float* fbufA     = fnorm_dst + na;
        float* fbufB     = fbufA + na * F1;
        int gE   = (nE + B - 1) / B;
        int gEF1 = (int)(((long long)nE * F1 + B - 1) / B);
        int gEF2 = (int)(((long long)nE * F2 + B - 1) / B);
        init_deg_kernel<<<gN, blk, 0, stream>>>(fnorm_src, fnorm_dst, n);
        count_deg_kernel<<<gE, blk, 0, stream>>>(src, dst, fnorm_src, fnorm_dst, nE);
        rsqrt_kernel<<<gN, blk, 0, stream>>>(fnorm_src, fnorm_dst, n);
        xw16_kernel<<<gN, blk, 0, stream>>>(x, W1, fnorm_src, fbufA, n);
        hipMemsetAsync(fbufB, 0, (size_t)n * F1 * sizeof(float), stream);
        scatter_kernel<F1><<<gEF1, blk, 0, stream>>>(src, dst, fbufA, fbufB, nE);
        combine_kernel<F1, true><<<gNF1, blk, 0, stream>>>(fbufB, fbufA, fnorm_dst, b1, fbufA, n);
        xw8_kernel<<<gN, blk, 0, stream>>>(fbufA, W2, fnorm_src, fbufB, n);
        hipMemsetAsync(fbufB + na * F2, 0, (size_t)n * F2 * sizeof(float), stream);
        scatter_kernel<F2><<<gEF2, blk, 0, stream>>>(src, dst, fbufB, fbufB + na * F2, nE);
        combine_kernel<F2, false><<<gNF2, blk, 0, stream>>>(fbufB + na * F2, fbufB, fnorm_dst,
                                                            b2, (float*)d_out, n);
    }
}

// Round 9
// 680.551 us; speedup vs baseline: 1.1919x; 1.1919x over previous
//
#include <hip/hip_runtime.h>

typedef unsigned int u32;

// GCN, 2-layer (16->16 relu, 16->8), DGL GraphConv norm='both', self-loops.
// N = 100000 nodes, E = 3.2M edges, f32, edge_index int32.
// Round 9: 2D counting sort (dst-bucket major, src-tile minor) + phase-
// serialized atomic-free aggregation. Evidence through r8: global f32 atomics
// are HBM-side RMWs (200-400MB writes @ ~1.2TB/s wall) -> must accumulate in
// LDS; src-ordering makes gathers L2-hot (r7: FETCH 123->9.4MB); temporal
// alignment must be enforced by stream-serialized phase launches (r6 showed
// natural alignment fails).

constexpr int F1 = 16;
constexpr int F2 = 8;
constexpr int HIST_N   = 100000;        // specialized node count
constexpr int HIST_U32 = HIST_N / 4;    // 25000 packed-u8 words
constexpr int NB_HIST  = 256;           // hist blocks
constexpr int RB       = 128;           // nodes per dst bucket
constexpr int NBUCK    = (HIST_N + RB - 1) / RB;  // 782
constexpr int NT       = 4;             // src tiles (src>>15 -> 0..3)
constexpr int TSH      = 15;
constexpr int NK       = NBUCK * NT;    // 3128 2D buckets
constexpr int P2B      = 512;           // partition/count blocks

// ---- src-degree: LDS packed-u8 histogram + byte-sum merge -> norm_src ----

__global__ void __launch_bounds__(256) hist_kernel(const int* __restrict__ idx,
                                                   u32* __restrict__ partial,
                                                   int nE, int per_block) {
    __shared__ u32 h[HIST_U32];
    for (int i = threadIdx.x; i < HIST_U32; i += 256) h[i] = 0u;
    __syncthreads();
    const int beg = blockIdx.x * per_block;
    const int end = min(nE, beg + per_block);
    for (int base = beg; base < end; base += 256 * 4) {
        int i = base + threadIdx.x * 4;
        if (i + 3 < end) {
            int4 v = *reinterpret_cast<const int4*>(idx + i);
            atomicAdd(&h[v.x >> 2], 1u << ((v.x & 3) << 3));
            atomicAdd(&h[v.y >> 2], 1u << ((v.y & 3) << 3));
            atomicAdd(&h[v.z >> 2], 1u << ((v.z & 3) << 3));
            atomicAdd(&h[v.w >> 2], 1u << ((v.w & 3) << 3));
        } else {
#pragma unroll
            for (int k = 0; k < 4; ++k)
                if (i + k < end) {
                    int v = idx[i + k];
                    atomicAdd(&h[v >> 2], 1u << ((v & 3) << 3));
                }
        }
    }
    __syncthreads();
    u32* out = partial + (size_t)blockIdx.x * HIST_U32;
    for (int i = threadIdx.x; i < HIST_U32; i += 256) out[i] = h[i];
}

__global__ void __launch_bounds__(256) merge_norm_kernel(const u32* __restrict__ partial,
                                                         float* __restrict__ norm) {
    int t = blockIdx.x * 256 + threadIdx.x;
    if (t >= HIST_U32) return;
    u32 s0 = 0, s1 = 0, s2 = 0, s3 = 0;
    const u32* p = partial + t;
    for (int b = 0; b < NB_HIST; ++b) {
        u32 v = p[(size_t)b * HIST_U32];
        s0 += v & 0xffu; s1 += (v >> 8) & 0xffu;
        s2 += (v >> 16) & 0xffu; s3 += v >> 24;
    }
    float4 o = make_float4(rsqrtf(1.f + (float)s0), rsqrtf(1.f + (float)s1),
                           rsqrtf(1.f + (float)s2), rsqrtf(1.f + (float)s3));
    *reinterpret_cast<float4*>(norm + (size_t)t * 4) = o;
}

// ---- 2D counting sort: key = (dst>>7)*NT + (src>>TSH) ----

__global__ void __launch_bounds__(256) bucket2_count_kernel(const int* __restrict__ src,
                                                            const int* __restrict__ dst,
                                                            u32* __restrict__ bcnt, int nE) {
    __shared__ u32 c[NK];
    for (int j = threadIdx.x; j < NK; j += 256) c[j] = 0;
    __syncthreads();
    for (int i = blockIdx.x * 256 + threadIdx.x; i < nE; i += 256 * P2B) {
        int key = (dst[i] >> 7) * NT + (src[i] >> TSH);
        atomicAdd(&c[key], 1u);
    }
    __syncthreads();
    for (int j = threadIdx.x; j < NK; j += 256)
        if (c[j]) atomicAdd(&bcnt[j], c[j]);
}

__global__ void __launch_bounds__(1024) bucket2_scan_kernel(const u32* __restrict__ bcnt,
                                                            u32* __restrict__ bbase,
                                                            u32* __restrict__ bcur) {
    __shared__ u32 s[1024];
    int t = threadIdx.x;
    u32 v[4];
    u32 sum = 0;
#pragma unroll
    for (int k = 0; k < 4; ++k) {
        int i = t * 4 + k;
        v[k] = (i < NK) ? bcnt[i] : 0u;
        sum += v[k];
    }
    s[t] = sum;
    __syncthreads();
    for (int off = 1; off < 1024; off <<= 1) {
        u32 a = (t >= off) ? s[t - off] : 0u;
        __syncthreads();
        s[t] += a;
        __syncthreads();
    }
    u32 base = (t > 0) ? s[t - 1] : 0u;
#pragma unroll
    for (int k = 0; k < 4; ++k) {
        int i = t * 4 + k;
        if (i <= NK) { bbase[i] = base; bcur[i] = base; }
        base += v[k];
    }
}

// pack: (dst_local<<17) | src   (src < 2^17, dst_local < 128)
__global__ void __launch_bounds__(256) partition2_kernel(const int* __restrict__ src,
                                                         const int* __restrict__ dst,
                                                         u32* __restrict__ part,
                                                         u32* __restrict__ bcur,
                                                         int nE, int per_block) {
    __shared__ u32 cnt[NK];
    for (int j = threadIdx.x; j < NK; j += 256) cnt[j] = 0;
    __syncthreads();
    const int beg = blockIdx.x * per_block;
    const int end = min(nE, beg + per_block);
    for (int i = beg + threadIdx.x; i < end; i += 256) {
        int key = (dst[i] >> 7) * NT + (src[i] >> TSH);
        atomicAdd(&cnt[key], 1u);
    }
    __syncthreads();
    // reserve: cnt[j] becomes the running global write cursor for key j
    for (int j = threadIdx.x; j < NK; j += 256) {
        u32 c = cnt[j];
        cnt[j] = c ? atomicAdd(&bcur[j], c) : 0u;
    }
    __syncthreads();
    for (int i = beg + threadIdx.x; i < end; i += 256) {
        int d = dst[i];
        int s = src[i];
        int key = (d >> 7) * NT + (s >> TSH);
        u32 r = atomicAdd(&cnt[key], 1u);
        part[r] = ((u32)(d & 127) << 17) | (u32)s;
    }
}

// norm_dst from sorted edges: bucket b = contiguous range [bbase[b*NT], bbase[(b+1)*NT])
__global__ void __launch_bounds__(256) norm_dst_kernel(const u32* __restrict__ part,
                                                       const u32* __restrict__ bbase,
                                                       float* __restrict__ norm_dst, int n) {
    __shared__ u32 c[RB];
    if (threadIdx.x < RB) c[threadIdx.x] = 0;
    __syncthreads();
    u32 beg = bbase[blockIdx.x * NT], end = bbase[(blockIdx.x + 1) * NT];
    for (u32 j = beg + threadIdx.x; j < end; j += 256)
        atomicAdd(&c[part[j] >> 17], 1u);
    __syncthreads();
    if (threadIdx.x < RB) {
        int node = blockIdx.x * RB + threadIdx.x;
        if (node < n) norm_dst[node] = rsqrtf(1.f + (float)c[threadIdx.x]);
    }
}

// ---- phase-serialized aggregation: one block per dst bucket, phase t only
// touches edges whose src is in tile t (2MB window, L2-resident because all
// blocks run the same phase - enforced by stream ordering between launches).
// LDS accumulate; merge into global acc with plain coalesced ops. LAST phase
// fuses the combine epilogue.
template <int F, bool FIRST, bool LAST, bool RELU>
__global__ void __launch_bounds__(512) agg_phase_kernel(
        const u32* __restrict__ part, const u32* __restrict__ bbase,
        const float* __restrict__ h, float* __restrict__ gacc,
        const float* __restrict__ norm_dst, const float* __restrict__ bias,
        float* __restrict__ out, int n, int t) {
    __shared__ float acc[RB * (F + 1)];
    for (int j = threadIdx.x; j < RB * (F + 1); j += 512) acc[j] = 0.f;
    __syncthreads();
    const int b = blockIdx.x;
    const u32 beg = bbase[b * NT + t], end = bbase[b * NT + t + 1];
    const int g = threadIdx.x / F;
    const int f = threadIdx.x % F;
    const int step = 512 / F;
    for (u32 j = beg + g; j < end; j += 2 * step) {
        u32 j2 = j + step;
        bool has1 = j2 < end;
        u32 w0 = part[j];
        u32 w1 = has1 ? part[j2] : w0;
        float v0 = h[(size_t)(w0 & 0x1FFFFu) * F + f];
        float v1 = has1 ? h[(size_t)(w1 & 0x1FFFFu) * F + f] : 0.f;
        atomicAdd(&acc[(w0 >> 17) * (F + 1) + f], v0);
        if (has1) atomicAdd(&acc[(w1 >> 17) * (F + 1) + f], v1);
    }
    __syncthreads();
    const int base_out = b * RB * F;
    for (int idx = threadIdx.x; idx < RB * F; idx += 512) {
        int gidx = base_out + idx;
        if (gidx >= n * F) break;
        int dl = idx / F, ff = idx - dl * F;
        float a = acc[dl * (F + 1) + ff];
        if (FIRST && !LAST) {
            gacc[gidx] = a;
        } else if (!LAST) {
            gacc[gidx] += a;
        } else {
            int node = b * RB + dl;
            float tot = (FIRST ? 0.f : gacc[gidx]) + a;
            float v = (tot + h[gidx]) * norm_dst[node] + bias[ff];
            if (RELU) v = fmaxf(v, 0.f);
            out[gidx] = v;
        }
    }
}

// ---- dense transforms ----

__global__ void xw16_kernel(const float* __restrict__ x, const float* __restrict__ W,
                            const float* __restrict__ norm_src,
                            float* __restrict__ h, int n) {
    __shared__ float Ws[256];
    int t = threadIdx.x;
    if (t < 256) Ws[t] = W[t];
    __syncthreads();
    int i = blockIdx.x * blockDim.x + t;
    if (i >= n) return;
    float xi[16];
    const float4* xp = reinterpret_cast<const float4*>(x + (size_t)i * 16);
    float4 v;
    v = xp[0]; xi[0]=v.x; xi[1]=v.y; xi[2]=v.z; xi[3]=v.w;
    v = xp[1]; xi[4]=v.x; xi[5]=v.y; xi[6]=v.z; xi[7]=v.w;
    v = xp[2]; xi[8]=v.x; xi[9]=v.y; xi[10]=v.z; xi[11]=v.w;
    v = xp[3]; xi[12]=v.x; xi[13]=v.y; xi[14]=v.z; xi[15]=v.w;
    float ns = norm_src[i];
    float o[16];
#pragma unroll
    for (int j = 0; j < 16; ++j) {
        float acc = 0.f;
#pragma unroll
        for (int k = 0; k < 16; ++k) acc = fmaf(xi[k], Ws[k * 16 + j], acc);
        o[j] = acc * ns;
    }
    float4* hp = reinterpret_cast<float4*>(h + (size_t)i * 16);
    hp[0] = make_float4(o[0], o[1], o[2], o[3]);
    hp[1] = make_float4(o[4], o[5], o[6], o[7]);
    hp[2] = make_float4(o[8], o[9], o[10], o[11]);
    hp[3] = make_float4(o[12], o[13], o[14], o[15]);
}

__global__ void xw8_kernel(const float* __restrict__ x, const float* __restrict__ W,
                           const float* __restrict__ norm_src,
                           float* __restrict__ h, int n) {
    __shared__ float Ws[128];
    int t = threadIdx.x;
    if (t < 128) Ws[t] = W[t];
    __syncthreads();
    int i = blockIdx.x * blockDim.x + t;
    if (i >= n) return;
    float xi[16];
    const float4* xp = reinterpret_cast<const float4*>(x + (size_t)i * 16);
    float4 v;
    v = xp[0]; xi[0]=v.x; xi[1]=v.y; xi[2]=v.z; xi[3]=v.w;
    v = xp[1]; xi[4]=v.x; xi[5]=v.y; xi[6]=v.z; xi[7]=v.w;
    v = xp[2]; xi[8]=v.x; xi[9]=v.y; xi[10]=v.z; xi[11]=v.w;
    v = xp[3]; xi[12]=v.x; xi[13]=v.y; xi[14]=v.z; xi[15]=v.w;
    float ns = norm_src[i];
    float o[8];
#pragma unroll
    for (int j = 0; j < 8; ++j) {
        float acc = 0.f;
#pragma unroll
        for (int k = 0; k < 16; ++k) acc = fmaf(xi[k], Ws[k * 8 + j], acc);
        o[j] = acc * ns;
    }
    float4* hp = reinterpret_cast<float4*>(h + (size_t)i * 8);
    hp[0] = make_float4(o[0], o[1], o[2], o[3]);
    hp[1] = make_float4(o[4], o[5], o[6], o[7]);
}

// ---- fallback (n != 100000 or small ws): scattered-atomic path ----

__global__ void init_deg_kernel(float* __restrict__ a, float* __restrict__ b, int n) {
    int i = blockIdx.x * 256 + threadIdx.x;
    if (i < n) { a[i] = 1.0f; b[i] = 1.0f; }
}
__global__ void count_deg_kernel(const int* __restrict__ src, const int* __restrict__ dst,
                                 float* __restrict__ dego, float* __restrict__ degi, int nE) {
    int e = blockIdx.x * 256 + threadIdx.x;
    if (e < nE) { atomicAdd(dego + src[e], 1.0f); atomicAdd(degi + dst[e], 1.0f); }
}
__global__ void rsqrt_kernel(float* __restrict__ a, float* __restrict__ b, int n) {
    int i = blockIdx.x * 256 + threadIdx.x;
    if (i < n) { a[i] = rsqrtf(a[i]); b[i] = rsqrtf(b[i]); }
}
template <int F>
__global__ void scatter_kernel(const int* __restrict__ src, const int* __restrict__ dst,
                               const float* __restrict__ h, float* __restrict__ agg,
                               int nE) {
    long long t = (long long)blockIdx.x * blockDim.x + threadIdx.x;
    if (t >= (long long)nE * F) return;
    int e = (int)(t / F);
    int f = (int)(t % F);
    atomicAdd(agg + (size_t)dst[e] * F + f, h[(size_t)src[e] * F + f]);
}
template <int F, bool RELU>
__global__ void combine_kernel(const float* __restrict__ agg, const float* __restrict__ h,
                               const float* __restrict__ norm_dst,
                               const float* __restrict__ b,
                               float* __restrict__ out, int n) {
    int t = blockIdx.x * 256 + threadIdx.x;
    if (t >= n * F) return;
    int i = t / F;
    int f = t % F;
    float v = (agg[t] + h[t]) * norm_dst[i] + b[f];
    if (RELU) v = fmaxf(v, 0.f);
    out[t] = v;
}

extern "C" void kernel_launch(void* const* d_in, const int* in_sizes, int n_in,
                              void* d_out, int out_size, void* d_ws, size_t ws_size,
                              hipStream_t stream) {
    const float* x  = (const float*)d_in[0];
    const float* W1 = (const float*)d_in[1];
    const float* b1 = (const float*)d_in[2];
    const float* W2 = (const float*)d_in[3];
    const float* b2 = (const float*)d_in[4];
    const int*   ei = (const int*)d_in[5];

    const int n  = in_sizes[0] / F1;   // 100000
    const int nE = in_sizes[5] / 2;    // 3200000
    const int* src = ei;
    const int* dst = ei + nE;

    const size_t na = ((size_t)n + 63) & ~(size_t)63;
    const int B = 256;
    dim3 blk(B);
    int gN   = (int)((n + B - 1) / B);
    int gNF1 = (int)((n * (size_t)F1 + B - 1) / B);
    int gNF2 = (int)((n * (size_t)F2 + B - 1) / B);

    // fast-path workspace layout
    float* norm_src = (float*)d_ws;                  // [na]
    float* norm_dst = norm_src + na;                 // [na]
    u32*   bbase    = (u32*)(norm_dst + na);         // [4096]
    u32*   bcur     = bbase + 4096;                  // [4096]
    u32*   bcnt     = bcur + 4096;                   // [4096]
    u32*   part     = bcnt + 4096;                   // [nE]
    float* bufA     = (float*)(part + nE);           // [na*16] h1'
    float* bufB     = bufA + na * F1;                // [na*16] gacc1 -> out1
    u32*   partial  = part;                          // NB_HIST*HIST_U32 overlays part+buf
    size_t need = ((size_t)2 * na + 3 * 4096 + (size_t)nE + 32 * na) * 4;
    size_t need_hist = ((size_t)2 * na + 3 * 4096) * 4 + (size_t)NB_HIST * HIST_U32 * 4;
    if (need_hist > need) need = need_hist;

    if (n == HIST_N && ws_size >= need) {
        int per_hist = (nE + NB_HIST - 1) / NB_HIST;
        int per_p2   = (nE + P2B - 1) / P2B;
        int gM = (HIST_U32 + B - 1) / B;

        // norm_src via u8-hist on src (partial overlays part/buf; consumed
        // before partition writes part)
        hist_kernel<<<NB_HIST, blk, 0, stream>>>(src, partial, nE, per_hist);
        merge_norm_kernel<<<gM, blk, 0, stream>>>(partial, norm_src);

        // 2D counting sort by (dst bucket, src tile)
        hipMemsetAsync(bcnt, 0, 4096 * sizeof(u32), stream);
        bucket2_count_kernel<<<P2B, blk, 0, stream>>>(src, dst, bcnt, nE);
        bucket2_scan_kernel<<<1, 1024, 0, stream>>>(bcnt, bbase, bcur);
        partition2_kernel<<<P2B, blk, 0, stream>>>(src, dst, part, bcur, nE, per_p2);
        norm_dst_kernel<<<NBUCK, blk, 0, stream>>>(part, bbase, norm_dst, n);

        // layer 1: h1' = xW1*norm_src; out1 = relu((A^T h1' + h1')*nd + b1)
        xw16_kernel<<<gN, blk, 0, stream>>>(x, W1, norm_src, bufA, n);
        agg_phase_kernel<F1, true,  false, false><<<NBUCK, dim3(512), 0, stream>>>(
            part, bbase, bufA, bufB, norm_dst, b1, bufB, n, 0);
        agg_phase_kernel<F1, false, false, false><<<NBUCK, dim3(512), 0, stream>>>(
            part, bbase, bufA, bufB, norm_dst, b1, bufB, n, 1);
        agg_phase_kernel<F1, false, false, false><<<NBUCK, dim3(512), 0, stream>>>(
            part, bbase, bufA, bufB, norm_dst, b1, bufB, n, 2);
        agg_phase_kernel<F1, false, true,  true ><<<NBUCK, dim3(512), 0, stream>>>(
            part, bbase, bufA, bufB, norm_dst, b1, bufB, n, 3);  // out1 -> bufB

        // layer 2: h2 = out1*W2*norm_src; out = (A^T h2 + h2)*nd + b2
        float* h2    = bufA;            // [na*8]
        float* gacc2 = bufA + na * F2;  // [na*8]
        xw8_kernel<<<gN, blk, 0, stream>>>(bufB, W2, norm_src, h2, n);
        agg_phase_kernel<F2, true,  false, false><<<NBUCK, dim3(512), 0, stream>>>(
            part, bbase, h2, gacc2, norm_dst, b2, (float*)d_out, n, 0);
        agg_phase_kernel<F2, false, false, false><<<NBUCK, dim3(512), 0, stream>>>(
            part, bbase, h2, gacc2, norm_dst, b2, (float*)d_out, n, 1);
        agg_phase_kernel<F2, false, false, false><<<NBUCK, dim3(512), 0, stream>>>(
            part, bbase, h2, gacc2, norm_dst, b2, (float*)d_out, n, 2);
        agg_phase_kernel<F2, false, true,  false><<<NBUCK, dim3(512), 0, stream>>>(
            part, bbase, h2, gacc2, norm_dst, b2, (float*)d_out, n, 3);
    } else {
        // fallback: scattered atomics (fits 13.7 MB ws)
        float* fnorm_src = (float*)d_ws;
        float* fnorm_dst = fnorm_src + na;
        float* fbufA     = fnorm_dst + na;
        float* fbufB     = fbufA + na * F1;
        int gE   = (nE + B - 1) / B;
        int gEF1 = (int)(((long long)nE * F1 + B - 1) / B);
        int gEF2 = (int)(((long long)nE * F2 + B - 1) / B);
        init_deg_kernel<<<gN, blk, 0, stream>>>(fnorm_src, fnorm_dst, n);
        count_deg_kernel<<<gE, blk, 0, stream>>>(src, dst, fnorm_src, fnorm_dst, nE);
        rsqrt_kernel<<<gN, blk, 0, stream>>>(fnorm_src, fnorm_dst, n);
        xw16_kernel<<<gN, blk, 0, stream>>>(x, W1, fnorm_src, fbufA, n);
        hipMemsetAsync(fbufB, 0, (size_t)n * F1 * sizeof(float), stream);
        scatter_kernel<F1><<<gEF1, blk, 0, stream>>>(src, dst, fbufA, fbufB, nE);
        combine_kernel<F1, true><<<gNF1, blk, 0, stream>>>(fbufB, fbufA, fnorm_dst, b1, fbufA, n);
        xw8_kernel<<<gN, blk, 0, stream>>>(fbufA, W2, fnorm_src, fbufB, n);
        hipMemsetAsync(fbufB + na * F2, 0, (size_t)n * F2 * sizeof(float), stream);
        scatter_kernel<F2><<<gEF2, blk, 0, stream>>>(src, dst, fbufB, fbufB + na * F2, nE);
        combine_kernel<F2, false><<<gNF2, blk, 0, stream>>>(fbufB + na * F2, fbufB, fnorm_dst,
                                                            b2, (float*)d_out, n);
    }
}

// Round 10
// 493.302 us; speedup vs baseline: 1.6444x; 1.3796x over previous
//
#include <hip/hip_runtime.h>

typedef unsigned int u32;

// GCN, 2-layer (16->16 relu, 16->8), DGL GraphConv norm='both', self-loops.
// N = 100000 nodes, E = 3.2M edges, f32, edge_index int32.
// Round 10: round-7 structure (src-bucketed sort -> L2-hot gathers -> global
// atomic scatter, 9.4MB FETCH / 200MB WRITE) with the ONE defect fixed: the
// per-item 10-step LDS binary search (53% VALU) is replaced by a one-time
// bisect + register-cached linear bucket advance (round 8's good half), at
// the original 4B/item granularity (round 8's bad half reverted).

constexpr int F1 = 16;
constexpr int F2 = 8;
constexpr int HIST_N   = 100000;        // specialized node count
constexpr int HIST_U32 = HIST_N / 4;    // 25000 packed-u8 words
constexpr int NB_HIST  = 256;           // hist blocks
constexpr int RB       = 128;           // nodes per src bucket
constexpr int NBUCK    = (HIST_N + RB - 1) / RB;  // 782
constexpr int P2B      = 512;           // partition/count blocks
constexpr int SCB      = 2048;          // scatter blocks (divisible by 8)

// ---- dst-degree: LDS packed-u8 histogram + byte-sum merge -> norm_dst ----

__global__ void __launch_bounds__(256) hist_kernel(const int* __restrict__ idx,
                                                   u32* __restrict__ partial,
                                                   int nE, int per_block) {
    __shared__ u32 h[HIST_U32];
    for (int i = threadIdx.x; i < HIST_U32; i += 256) h[i] = 0u;
    __syncthreads();
    const int beg = blockIdx.x * per_block;
    const int end = min(nE, beg + per_block);
    for (int base = beg; base < end; base += 256 * 4) {
        int i = base + threadIdx.x * 4;
        if (i + 3 < end) {
            int4 v = *reinterpret_cast<const int4*>(idx + i);
            atomicAdd(&h[v.x >> 2], 1u << ((v.x & 3) << 3));
            atomicAdd(&h[v.y >> 2], 1u << ((v.y & 3) << 3));
            atomicAdd(&h[v.z >> 2], 1u << ((v.z & 3) << 3));
            atomicAdd(&h[v.w >> 2], 1u << ((v.w & 3) << 3));
        } else {
#pragma unroll
            for (int k = 0; k < 4; ++k)
                if (i + k < end) {
                    int v = idx[i + k];
                    atomicAdd(&h[v >> 2], 1u << ((v & 3) << 3));
                }
        }
    }
    __syncthreads();
    u32* out = partial + (size_t)blockIdx.x * HIST_U32;
    for (int i = threadIdx.x; i < HIST_U32; i += 256) out[i] = h[i];
}

__global__ void __launch_bounds__(256) merge_norm_kernel(const u32* __restrict__ partial,
                                                         float* __restrict__ norm) {
    int t = blockIdx.x * 256 + threadIdx.x;
    if (t >= HIST_U32) return;
    u32 s0 = 0, s1 = 0, s2 = 0, s3 = 0;
    const u32* p = partial + t;
    for (int b = 0; b < NB_HIST; ++b) {
        u32 v = p[(size_t)b * HIST_U32];
        s0 += v & 0xffu; s1 += (v >> 8) & 0xffu;
        s2 += (v >> 16) & 0xffu; s3 += v >> 24;
    }
    float4 o = make_float4(rsqrtf(1.f + (float)s0), rsqrtf(1.f + (float)s1),
                           rsqrtf(1.f + (float)s2), rsqrtf(1.f + (float)s3));
    *reinterpret_cast<float4*>(norm + (size_t)t * 4) = o;
}

// ---- src-bucket counting sort ----

__global__ void __launch_bounds__(256) bucket_count_kernel(const int* __restrict__ src,
                                                           u32* __restrict__ bcnt, int nE) {
    __shared__ u32 c[NBUCK];
    for (int j = threadIdx.x; j < NBUCK; j += 256) c[j] = 0;
    __syncthreads();
    for (int i = blockIdx.x * 256 + threadIdx.x; i < nE; i += 256 * P2B)
        atomicAdd(&c[src[i] >> 7], 1u);
    __syncthreads();
    for (int j = threadIdx.x; j < NBUCK; j += 256)
        if (c[j]) atomicAdd(&bcnt[j], c[j]);
}

__global__ void __launch_bounds__(1024) bucket_scan_kernel(const u32* __restrict__ bcnt,
                                                           u32* __restrict__ bbase,
                                                           u32* __restrict__ bcur) {
    __shared__ u32 s[1024];
    int t = threadIdx.x;
    u32 v = (t < NBUCK) ? bcnt[t] : 0;
    s[t] = v;
    __syncthreads();
    for (int off = 1; off < 1024; off <<= 1) {
        u32 a = (t >= off) ? s[t - off] : 0;
        __syncthreads();
        s[t] += a;
        __syncthreads();
    }
    if (t < NBUCK) {
        u32 ex = s[t] - v;
        bbase[t] = ex;
        bcur[t] = ex;
        if (t == NBUCK - 1) bbase[NBUCK] = s[t];
    }
}

// pack: (src_local<<17) | dst   (dst < 2^17, src_local < 128)
__global__ void __launch_bounds__(256) partition_kernel(const int* __restrict__ src,
                                                        const int* __restrict__ dst,
                                                        u32* __restrict__ part,
                                                        u32* __restrict__ bcur,
                                                        int nE, int per_block) {
    __shared__ u32 cnt[NBUCK];
    __shared__ u32 gb[NBUCK];
    for (int j = threadIdx.x; j < NBUCK; j += 256) cnt[j] = 0;
    __syncthreads();
    const int beg = blockIdx.x * per_block;
    const int end = min(nE, beg + per_block);
    for (int i = beg + threadIdx.x; i < end; i += 256)
        atomicAdd(&cnt[src[i] >> 7], 1u);
    __syncthreads();
    for (int j = threadIdx.x; j < NBUCK; j += 256) {
        u32 c = cnt[j];
        gb[j] = c ? atomicAdd(&bcur[j], c) : 0u;
        cnt[j] = 0;
    }
    __syncthreads();
    for (int i = beg + threadIdx.x; i < end; i += 256) {
        int s = src[i];
        int b = s >> 7;
        u32 r = atomicAdd(&cnt[b], 1u);
        part[gb[b] + r] = ((u32)(s & 127) << 17) | (u32)dst[i];
    }
}

// norm_src from partitioned edges: per-bucket src_local counts
__global__ void __launch_bounds__(256) norm_src_kernel(const u32* __restrict__ part,
                                                       const u32* __restrict__ bbase,
                                                       float* __restrict__ norm_src, int n) {
    __shared__ u32 c[RB];
    if (threadIdx.x < RB) c[threadIdx.x] = 0;
    __syncthreads();
    u32 beg = bbase[blockIdx.x], end = bbase[blockIdx.x + 1];
    for (u32 j = beg + threadIdx.x; j < end; j += 256)
        atomicAdd(&c[part[j] >> 17], 1u);
    __syncthreads();
    if (threadIdx.x < RB) {
        int node = blockIdx.x * RB + threadIdx.x;
        if (node < n) norm_src[node] = rsqrtf(1.f + (float)c[threadIdx.x]);
    }
}

// ---- scatter: gather h[src] (L1/L2-hot via src-bucketed order), global
// atomicAdd to agg[dst]. One item = (edge, feature); F consecutive lanes share
// an edge -> the gather is one 64B line and the atomics are line-merged per
// wave. Bucket id via one-time bisect + register linear advance (e monotone).
template <int F>
__global__ void __launch_bounds__(256) scatter_bucketed_kernel(
        const u32* __restrict__ part, const u32* __restrict__ bbase_g,
        const float* __restrict__ h, float* __restrict__ agg, int nE) {
    __shared__ u32 bb[NBUCK + 1];
    for (int i = threadIdx.x; i < NBUCK + 1; i += 256) bb[i] = bbase_g[i];
    __syncthreads();
    // bijective XCD swizzle: each XCD gets a contiguous chunk of blocks ->
    // contiguous src-bucket range -> exclusive L2 window.
    const int nb = (int)gridDim.x;
    const int q = nb / 8, r = nb % 8;
    const int xc = (int)blockIdx.x % 8, ix = (int)blockIdx.x / 8;
    const int sb = (xc < r ? xc * (q + 1) : r * (q + 1) + (xc - r) * q) + ix;

    constexpr int fsh = (F == 16) ? 4 : 3;
    const long long total = (long long)nE * F;
    const long long per = (total + nb - 1) / nb;
    const long long beg = (long long)sb * per;
    const long long end = (beg + per < total) ? beg + per : total;

    long long t0 = beg + threadIdx.x;
    if (t0 >= end) return;
    // one-time bisect: bb[lo] <= e0 < bb[lo+1]
    int e0 = (int)(t0 >> fsh);
    int lo = 0, hi = NBUCK;
#pragma unroll
    for (int s = 0; s < 10; ++s) {
        int mid = (lo + hi) >> 1;
        if (bb[mid] <= (u32)e0) lo = mid; else hi = mid;
    }
    u32 nextb = bb[lo + 1];
    for (long long t = t0; t < end; t += 256) {
        int e = (int)(t >> fsh);
        int f = (int)(t & (F - 1));
        while ((u32)e >= nextb) { ++lo; nextb = bb[lo + 1]; }
        u32 w = __builtin_nontemporal_load(part + e);
        int s = lo * RB + (int)(w >> 17);
        int d = (int)(w & 0x1FFFFu);
        atomicAdd(agg + (size_t)d * F + f, h[(size_t)s * F + f]);
    }
}

// ---- dense transforms ----

__global__ void xw16_kernel(const float* __restrict__ x, const float* __restrict__ W,
                            const float* __restrict__ norm_src,
                            float* __restrict__ h, int n) {
    __shared__ float Ws[256];
    int t = threadIdx.x;
    if (t < 256) Ws[t] = W[t];
    __syncthreads();
    int i = blockIdx.x * blockDim.x + t;
    if (i >= n) return;
    float xi[16];
    const float4* xp = reinterpret_cast<const float4*>(x + (size_t)i * 16);
    float4 v;
    v = xp[0]; xi[0]=v.x; xi[1]=v.y; xi[2]=v.z; xi[3]=v.w;
    v = xp[1]; xi[4]=v.x; xi[5]=v.y; xi[6]=v.z; xi[7]=v.w;
    v = xp[2]; xi[8]=v.x; xi[9]=v.y; xi[10]=v.z; xi[11]=v.w;
    v = xp[3]; xi[12]=v.x; xi[13]=v.y; xi[14]=v.z; xi[15]=v.w;
    float ns = norm_src[i];
    float o[16];
#pragma unroll
    for (int j = 0; j < 16; ++j) {
        float acc = 0.f;
#pragma unroll
        for (int k = 0; k < 16; ++k) acc = fmaf(xi[k], Ws[k * 16 + j], acc);
        o[j] = acc * ns;
    }
    float4* hp = reinterpret_cast<float4*>(h + (size_t)i * 16);
    hp[0] = make_float4(o[0], o[1], o[2], o[3]);
    hp[1] = make_float4(o[4], o[5], o[6], o[7]);
    hp[2] = make_float4(o[8], o[9], o[10], o[11]);
    hp[3] = make_float4(o[12], o[13], o[14], o[15]);
}

__global__ void xw8_kernel(const float* __restrict__ x, const float* __restrict__ W,
                           const float* __restrict__ norm_src,
                           float* __restrict__ h, int n) {
    __shared__ float Ws[128];
    int t = threadIdx.x;
    if (t < 128) Ws[t] = W[t];
    __syncthreads();
    int i = blockIdx.x * blockDim.x + t;
    if (i >= n) return;
    float xi[16];
    const float4* xp = reinterpret_cast<const float4*>(x + (size_t)i * 16);
    float4 v;
    v = xp[0]; xi[0]=v.x; xi[1]=v.y; xi[2]=v.z; xi[3]=v.w;
    v = xp[1]; xi[4]=v.x; xi[5]=v.y; xi[6]=v.z; xi[7]=v.w;
    v = xp[2]; xi[8]=v.x; xi[9]=v.y; xi[10]=v.z; xi[11]=v.w;
    v = xp[3]; xi[12]=v.x; xi[13]=v.y; xi[14]=v.z; xi[15]=v.w;
    float ns = norm_src[i];
    float o[8];
#pragma unroll
    for (int j = 0; j < 8; ++j) {
        float acc = 0.f;
#pragma unroll
        for (int k = 0; k < 16; ++k) acc = fmaf(xi[k], Ws[k * 8 + j], acc);
        o[j] = acc * ns;
    }
    float4* hp = reinterpret_cast<float4*>(h + (size_t)i * 8);
    hp[0] = make_float4(o[0], o[1], o[2], o[3]);
    hp[1] = make_float4(o[4], o[5], o[6], o[7]);
}

// out = ((agg + h_self) * norm_dst + b), optional relu (elementwise, in-place ok)
template <int F, bool RELU>
__global__ void combine_kernel(const float* __restrict__ agg, const float* __restrict__ h,
                               const float* __restrict__ norm_dst,
                               const float* __restrict__ b,
                               float* __restrict__ out, int n) {
    int t = blockIdx.x * 256 + threadIdx.x;
    if (t >= n * F) return;
    int i = t / F;
    int f = t % F;
    float v = (agg[t] + h[t]) * norm_dst[i] + b[f];
    if (RELU) v = fmaxf(v, 0.f);
    out[t] = v;
}

// ---- fallback (n != 100000 or small ws): scattered-atomic path ----

__global__ void init_deg_kernel(float* __restrict__ a, float* __restrict__ b, int n) {
    int i = blockIdx.x * 256 + threadIdx.x;
    if (i < n) { a[i] = 1.0f; b[i] = 1.0f; }
}
__global__ void count_deg_kernel(const int* __restrict__ src, const int* __restrict__ dst,
                                 float* __restrict__ dego, float* __restrict__ degi, int nE) {
    int e = blockIdx.x * 256 + threadIdx.x;
    if (e < nE) { atomicAdd(dego + src[e], 1.0f); atomicAdd(degi + dst[e], 1.0f); }
}
__global__ void rsqrt_kernel(float* __restrict__ a, float* __restrict__ b, int n) {
    int i = blockIdx.x * 256 + threadIdx.x;
    if (i < n) { a[i] = rsqrtf(a[i]); b[i] = rsqrtf(b[i]); }
}
template <int F>
__global__ void scatter_kernel(const int* __restrict__ src, const int* __restrict__ dst,
                               const float* __restrict__ h, float* __restrict__ agg,
                               int nE) {
    long long t = (long long)blockIdx.x * blockDim.x + threadIdx.x;
    if (t >= (long long)nE * F) return;
    int e = (int)(t / F);
    int f = (int)(t % F);
    atomicAdd(agg + (size_t)dst[e] * F + f, h[(size_t)src[e] * F + f]);
}

extern "C" void kernel_launch(void* const* d_in, const int* in_sizes, int n_in,
                              void* d_out, int out_size, void* d_ws, size_t ws_size,
                              hipStream_t stream) {
    const float* x  = (const float*)d_in[0];
    const float* W1 = (const float*)d_in[1];
    const float* b1 = (const float*)d_in[2];
    const float* W2 = (const float*)d_in[3];
    const float* b2 = (const float*)d_in[4];
    const int*   ei = (const int*)d_in[5];

    const int n  = in_sizes[0] / F1;   // 100000
    const int nE = in_sizes[5] / 2;    // 3200000
    const int* src = ei;
    const int* dst = ei + nE;

    const size_t na = ((size_t)n + 63) & ~(size_t)63;
    const int B = 256;
    dim3 blk(B);
    int gN   = (int)((n + B - 1) / B);
    int gNF1 = (int)((n * (size_t)F1 + B - 1) / B);
    int gNF2 = (int)((n * (size_t)F2 + B - 1) / B);

    // fast-path workspace layout
    float* norm_src = (float*)d_ws;                  // [na]
    float* norm_dst = norm_src + na;                 // [na]
    u32*   bbase    = (u32*)(norm_dst + na);         // [1024]
    u32*   bcur     = bbase + 1024;                  // [1024]
    u32*   bcnt     = bcur + 1024;                   // [1024]
    u32*   part     = bcnt + 1024;                   // [nE]
    float* bufA     = (float*)(part + nE);           // [na*16] h1' then out1
    float* bufB     = bufA + na * F1;                // [na*16] agg1; then h2 | agg2
    u32*   partial  = part;                          // NB_HIST*HIST_U32 overlays part+buf
    size_t need = ((size_t)2 * na + 3 * 1024 + (size_t)nE + 32 * na) * 4;
    size_t need_hist = ((size_t)2 * na + 3 * 1024) * 4 + (size_t)NB_HIST * HIST_U32 * 4;
    if (need_hist > need) need = need_hist;

    if (n == HIST_N && ws_size >= need) {
        int per_hist = (nE + NB_HIST - 1) / NB_HIST;
        int per_p2   = (nE + P2B - 1) / P2B;
        int gM = (HIST_U32 + B - 1) / B;

        // norm_dst via u8-hist on dst (partial overlays part/buf region; done
        // before partition writes part)
        hist_kernel<<<NB_HIST, blk, 0, stream>>>(dst, partial, nE, per_hist);
        merge_norm_kernel<<<gM, blk, 0, stream>>>(partial, norm_dst);

        // counting sort of edges by src bucket (src>>7)
        hipMemsetAsync(bcnt, 0, NBUCK * sizeof(u32), stream);
        bucket_count_kernel<<<P2B, blk, 0, stream>>>(src, bcnt, nE);
        bucket_scan_kernel<<<1, 1024, 0, stream>>>(bcnt, bbase, bcur);
        partition_kernel<<<P2B, blk, 0, stream>>>(src, dst, part, bcur, nE, per_p2);
        norm_src_kernel<<<NBUCK, blk, 0, stream>>>(part, bbase, norm_src, n);

        // layer 1: h1' = xW1*norm_src; agg1 = A^T h1'; out1 = relu((agg1+h1')*nd+b1)
        xw16_kernel<<<gN, blk, 0, stream>>>(x, W1, norm_src, bufA, n);
        hipMemsetAsync(bufB, 0, (size_t)n * F1 * sizeof(float), stream);
        scatter_bucketed_kernel<F1><<<SCB, blk, 0, stream>>>(part, bbase, bufA, bufB, nE);
        combine_kernel<F1, true><<<gNF1, blk, 0, stream>>>(bufB, bufA, norm_dst, b1,
                                                           bufA, n);  // out1 -> bufA

        // layer 2: h2 = out1*W2*norm_src (bufB low half); agg2 = bufB high half
        float* h2   = bufB;
        float* agg2 = bufB + na * F2;
        xw8_kernel<<<gN, blk, 0, stream>>>(bufA, W2, norm_src, h2, n);
        hipMemsetAsync(agg2, 0, (size_t)n * F2 * sizeof(float), stream);
        scatter_bucketed_kernel<F2><<<SCB, blk, 0, stream>>>(part, bbase, h2, agg2, nE);
        combine_kernel<F2, false><<<gNF2, blk, 0, stream>>>(agg2, h2, norm_dst, b2,
                                                            (float*)d_out, n);
    } else {
        // fallback: scattered atomics (fits 13.7 MB ws)
        float* fnorm_src = (float*)d_ws;
        float* fnorm_dst = fnorm_src + na;
        float* fbufA     = fnorm_dst + na;
        float* fbufB     = fbufA + na * F1;
        int gE   = (nE + B - 1) / B;
        int gEF1 = (int)(((long long)nE * F1 + B - 1) / B);
        int gEF2 = (int)(((long long)nE * F2 + B - 1) / B);
        init_deg_kernel<<<gN, blk, 0, stream>>>(fnorm_src, fnorm_dst, n);
        count_deg_kernel<<<gE, blk, 0, stream>>>(src, dst, fnorm_src, fnorm_dst, nE);
        rsqrt_kernel<<<gN, blk, 0, stream>>>(fnorm_src, fnorm_dst, n);
        xw16_kernel<<<gN, blk, 0, stream>>>(x, W1, fnorm_src, fbufA, n);
        hipMemsetAsync(fbufB, 0, (size_t)n * F1 * sizeof(float), stream);
        scatter_kernel<F1><<<gEF1, blk, 0, stream>>>(src, dst, fbufA, fbufB, nE);
        combine_kernel<F1, true><<<gNF1, blk, 0, stream>>>(fbufB, fbufA, fnorm_dst, b1, fbufA, n);
        xw8_kernel<<<gN, blk, 0, stream>>>(fbufA, W2, fnorm_src, fbufB, n);
        hipMemsetAsync(fbufB + na * F2, 0, (size_t)n * F2 * sizeof(float), stream);
        scatter_kernel<F2><<<gEF2, blk, 0, stream>>>(src, dst, fbufB, fbufB + na * F2, nE);
        combine_kernel<F2, false><<<gNF2, blk, 0, stream>>>(fbufB + na * F2, fbufB, fnorm_dst,
                                                            b2, (float*)d_out, n);
    }
}